// Round 1
// baseline (228.152 us; speedup 1.0000x reference)
//
#include <hip/hip_runtime.h>

// IWT (inverse 2x2 Haar): x (32, 256, 64, 64) f32 -> out (32, 64, 128, 128) f32
// Input channel dim = 64 groups * 4 subbands {cA, cH, cV, cD}.
// out[2h  ][2w  ] = (a + h + v + d) * 0.5
// out[2h  ][2w+1] = (a + h - v - d) * 0.5
// out[2h+1][2w  ] = (a - h + v - d) * 0.5
// out[2h+1][2w+1] = (a - h - v + d) * 0.5
//
// v2: widen loads to float4 (16 B/lane — the coalescing sweet spot; the
// 6.29 TB/s copy ceiling is measured with float4). Each thread handles 4
// consecutive input w per subband -> an 8-wide x 2-row output patch.
//   Loads: 4x global_load_dwordx4; each wave load = 64 contiguous float4
//          (w4 0..15 x 4 consecutive h rows) = dense 1 KiB.
//   Stores: 4x global_store_dwordx4; per-thread 32 B contiguous per row.
//          Lane pattern is stride-2 float4, but the paired store fills the
//          complementary halves of the same 64 B lines in the same wave, so
//          L2 lines are fully dirty before writeback.

#define BB 32
#define CC 64
#define HH 64
#define WW 64

__global__ __launch_bounds__(256) void iwt_kernel(const float4* __restrict__ xv,
                                                  float4* __restrict__ ov) {
    int tid = blockIdx.x * blockDim.x + threadIdx.x;

    int w4 = tid & 15;           // which float4 within the input row (0..15)
    int h  = (tid >> 4) & 63;    // input row
    int bc = tid >> 10;          // 0 .. B*C-1 (2047)

    // input float4 idx for subband s: (4*bc + s)*1024 + h*16 + w4
    int base = (bc << 12) + (h << 4) + w4;
    float4 a  = xv[base];
    float4 hh = xv[base + 1024];
    float4 v  = xv[base + 2048];
    float4 d  = xv[base + 3072];

    // butterfly per component: p=a+d, q=a-d, r=h+v, s=h-v
    // o00=(p+r)/2, o01=(q+s)/2, o10=(q-s)/2, o11=(p-r)/2
    float px = a.x + d.x, qx = a.x - d.x, rx = hh.x + v.x, sx = hh.x - v.x;
    float py = a.y + d.y, qy = a.y - d.y, ry = hh.y + v.y, sy = hh.y - v.y;
    float pz = a.z + d.z, qz = a.z - d.z, rz = hh.z + v.z, sz = hh.z - v.z;
    float pw = a.w + d.w, qw = a.w - d.w, rw = hh.w + v.w, sw = hh.w - v.w;

    float4 r0a, r0b, r1a, r1b;
    // row 2h, out w = 8*w4 .. 8*w4+7
    r0a.x = (px + rx) * 0.5f;   // o00 (in w comp x)
    r0a.y = (qx + sx) * 0.5f;   // o01
    r0a.z = (py + ry) * 0.5f;   // o00 (comp y)
    r0a.w = (qy + sy) * 0.5f;   // o01
    r0b.x = (pz + rz) * 0.5f;   // o00 (comp z)
    r0b.y = (qz + sz) * 0.5f;   // o01
    r0b.z = (pw + rw) * 0.5f;   // o00 (comp w)
    r0b.w = (qw + sw) * 0.5f;   // o01
    // row 2h+1
    r1a.x = (qx - sx) * 0.5f;   // o10
    r1a.y = (px - rx) * 0.5f;   // o11
    r1a.z = (qy - sy) * 0.5f;
    r1a.w = (py - ry) * 0.5f;
    r1b.x = (qz - sz) * 0.5f;
    r1b.y = (pz - rz) * 0.5f;
    r1b.z = (qw - sw) * 0.5f;
    r1b.w = (pw - rw) * 0.5f;

    // out float4 idx for row y: (bc*128 + y)*32 + k, k in 0..31
    // row 2h: bc*4096 + h*64 + 2*w4 ; row 2h+1: +32
    int obase = (bc << 12) + (h << 6) + (w4 << 1);
    ov[obase]      = r0a;
    ov[obase + 1]  = r0b;
    ov[obase + 32] = r1a;
    ov[obase + 33] = r1b;
}

extern "C" void kernel_launch(void* const* d_in, const int* in_sizes, int n_in,
                              void* d_out, int out_size, void* d_ws, size_t ws_size,
                              hipStream_t stream) {
    const float4* x = (const float4*)d_in[0];
    float4* out = (float4*)d_out;

    const int total_threads = BB * CC * HH * (WW / 4);  // 2,097,152
    const int block = 256;
    const int grid = total_threads / block;             // 8192

    iwt_kernel<<<grid, block, 0, stream>>>(x, out);
}

// Round 4
// 227.065 us; speedup vs baseline: 1.0048x; 1.0048x over previous
//
#include <hip/hip_runtime.h>

// IWT (inverse 2x2 Haar): x (32, 256, 64, 64) f32 -> out (32, 64, 128, 128) f32
// Input channel dim = 64 groups * 4 subbands {cA, cH, cV, cD}.
// out[2h  ][2w  ] = (a + h + v + d) * 0.5
// out[2h  ][2w+1] = (a + h - v - d) * 0.5
// out[2h+1][2w  ] = (a - h + v - d) * 0.5
// out[2h+1][2w+1] = (a - h - v + d) * 0.5
//
// v3b: persistent grid-stride kernel (v3 with native-vector NT stores —
// __builtin_nontemporal_store rejects HIP_vector_type float4, needs a
// clang ext_vector_type). Resubmitted after infra failure (round 3).
//   Evidence: v1 (8B dense loads / dense stores) == v2 (16B dense loads /
//   stride-2 stores) == ~80.5us, HBM 31%, VALU 4%, occupancy 63% -> the
//   limiter is NOT instruction shape; it's wave churn + per-wave MLP
//   (32768 one-shot workgroups, each wave stalls vmcnt(0) for its whole
//   life). Everything that sustains 6+ TB/s on this chip (fills, float4
//   copy) is a loop kernel. So: 2048 blocks x 256 threads, 8 tiles/thread,
//   fully unrolled (2-tile batched loads) -> sustained loads-in-flight per
//   wave, 16x less launch churn.
//   Mapping is v1's fully-dense one: float2 loads (512B/instr dense),
//   float4 stores (1KB/instr dense), 1 line-request per 64B on both sides.
//   Stores are nontemporal: output is write-once; keep the LLC for the
//   input (input 128MiB + output 128MiB exactly fill the 256MiB L3; NT
//   stores stop the writes from evicting the input between iterations).

#define BB 32
#define CC 64
#define HH 64
#define WW 64

#define NBLOCK  2048
#define NTHREAD 256
#define STRIDE  (NBLOCK * NTHREAD)            // 524,288 threads
#define NTILES  (BB * CC * HH * (WW / 2))     // 4,194,304 float2-tiles
#define ITERS   (NTILES / STRIDE)             // 8 tiles per thread

typedef float f32x2 __attribute__((ext_vector_type(2)));
typedef float f32x4 __attribute__((ext_vector_type(4)));

__global__ __launch_bounds__(NTHREAD) void iwt_kernel(const f32x2* __restrict__ xv,
                                                      f32x4* __restrict__ ov) {
    int tid = blockIdx.x * NTHREAD + threadIdx.x;

    #pragma unroll
    for (int it = 0; it < ITERS; it += 2) {
        int tA = tid + it * STRIDE;
        int tB = tA + STRIDE;

        // f32x2 idx for subband s of tile t: (4*bc + s)*2048 + h*32 + w2
        //   w2 = t & 31, h = (t>>5) & 63, bc = t >> 11
        int baseA = ((tA >> 11) << 13) + (((tA >> 5) & 63) << 5) + (tA & 31);
        int baseB = ((tB >> 11) << 13) + (((tB >> 5) & 63) << 5) + (tB & 31);

        // Batch both tiles' loads so 8 independent dwordx2 are in flight.
        f32x2 aA = xv[baseA];
        f32x2 hA = xv[baseA + 2048];
        f32x2 vA = xv[baseA + 4096];
        f32x2 dA = xv[baseA + 6144];
        f32x2 aB = xv[baseB];
        f32x2 hB = xv[baseB + 2048];
        f32x2 vB = xv[baseB + 4096];
        f32x2 dB = xv[baseB + 6144];

        {   // tile A
            float px = aA.x + dA.x, qx = aA.x - dA.x, rx = hA.x + vA.x, sx = hA.x - vA.x;
            float py = aA.y + dA.y, qy = aA.y - dA.y, ry = hA.y + vA.y, sy = hA.y - vA.y;
            f32x4 r0, r1;
            r0.x = (px + rx) * 0.5f;  r0.y = (qx + sx) * 0.5f;   // row 2h:   o00 o01
            r0.z = (py + ry) * 0.5f;  r0.w = (qy + sy) * 0.5f;
            r1.x = (qx - sx) * 0.5f;  r1.y = (px - rx) * 0.5f;   // row 2h+1: o10 o11
            r1.z = (qy - sy) * 0.5f;  r1.w = (py - ry) * 0.5f;
            // out f32x4 idx: row 2h at bc*4096 + h*64 + w2; row 2h+1 at +32
            int ob = ((tA >> 11) << 12) + (((tA >> 5) & 63) << 6) + (tA & 31);
            __builtin_nontemporal_store(r0, &ov[ob]);
            __builtin_nontemporal_store(r1, &ov[ob + 32]);
        }
        {   // tile B
            float px = aB.x + dB.x, qx = aB.x - dB.x, rx = hB.x + vB.x, sx = hB.x - vB.x;
            float py = aB.y + dB.y, qy = aB.y - dB.y, ry = hB.y + vB.y, sy = hB.y - vB.y;
            f32x4 r0, r1;
            r0.x = (px + rx) * 0.5f;  r0.y = (qx + sx) * 0.5f;
            r0.z = (py + ry) * 0.5f;  r0.w = (qy + sy) * 0.5f;
            r1.x = (qx - sx) * 0.5f;  r1.y = (px - rx) * 0.5f;
            r1.z = (qy - sy) * 0.5f;  r1.w = (py - ry) * 0.5f;
            int ob = ((tB >> 11) << 12) + (((tB >> 5) & 63) << 6) + (tB & 31);
            __builtin_nontemporal_store(r0, &ov[ob]);
            __builtin_nontemporal_store(r1, &ov[ob + 32]);
        }
    }
}

extern "C" void kernel_launch(void* const* d_in, const int* in_sizes, int n_in,
                              void* d_out, int out_size, void* d_ws, size_t ws_size,
                              hipStream_t stream) {
    const f32x2* x = (const f32x2*)d_in[0];
    f32x4* out = (f32x4*)d_out;

    iwt_kernel<<<NBLOCK, NTHREAD, 0, stream>>>(x, out);
}